// Round 2
// baseline (220.200 us; speedup 1.0000x reference)
//
#include <hip/hip_runtime.h>
#include <math.h>

#define MAX_OBJ 64
#define ITEMS 8
#define BCH 2
#define TOPK_CH 32

// ---------------------------------------------------------------------------
// ws layout:
//   double sums[3]     : conf_pos_sum, loc_sum, hardneg_sum
//   u32    counter     : completion counter for fused finalize
//   int    n_pos[B]
//   u64    prior_fo[B*n_obj]  : packed (iou_bits<<32)|(0xFFFFFFFF-p)
//   u32    hist[B][4][256]    : per-row per-round radix histograms
//   float  conf_neg[B*P]
//   u8     best_u8[B*P]       : bit7 = (iou>=0.5), bits0-6 = best obj
// ---------------------------------------------------------------------------

__global__ void mbl_init(double* __restrict__ sums, unsigned* __restrict__ counter,
                         int* __restrict__ n_pos, unsigned long long* __restrict__ prior_fo,
                         unsigned* __restrict__ hist, int B, int n_obj, int histN) {
  const int i = blockIdx.x * 256 + threadIdx.x;
  if (i < 3) sums[i] = 0.0;
  if (i == 3) *counter = 0u;
  if (i < B) n_pos[i] = 0;
  if (i < B * n_obj) prior_fo[i] = 0ULL;
  if (i < histN) hist[i] = 0u;
}

// Phase A: per-prior best object (u8) + per-object best prior (packed u64 atomicMax).
template <int NOBJ>
__global__ __launch_bounds__(256) void mbl_match(
    const float* __restrict__ boxes, const float* __restrict__ priors,
    unsigned long long* __restrict__ prior_fo, unsigned char* __restrict__ best_u8,
    int P, int n_obj, int B) {
  const int tid = threadIdx.x;
  const int b0 = blockIdx.y * BCH;
  __shared__ float4 s_box[BCH][NOBJ][2];  // {lo0,lo1,lo2,hi0},{hi1,hi2,vol,pad}
  __shared__ unsigned long long s_part[4][NOBJ];

  for (int i = tid; i < BCH * NOBJ; i += 256) {
    const int bb = i / NOBJ, oo = i % NOBJ;
    float4 v0, v1;
    if (oo < n_obj && b0 + bb < B) {
      const float* bx = boxes + ((size_t)(b0 + bb) * n_obj + oo) * 6;
      const float l0 = bx[0], l1 = bx[1], l2 = bx[2];
      const float h0 = bx[3], h1 = bx[4], h2 = bx[5];
      v0 = make_float4(l0, l1, l2, h0);
      v1 = make_float4(h1, h2, ((h0 - l0) * (h1 - l1)) * (h2 - l2), 0.f);
    } else {  // padding object: no overlap with anything, vol 0
      v0 = make_float4(1e18f, 1e18f, 1e18f, 1e18f);
      v1 = make_float4(1e18f, 1e18f, 0.f, 0.f);
    }
    s_box[bb][oo][0] = v0;
    s_box[bb][oo][1] = v1;
  }
  __syncthreads();

  // per-thread prior prep (registers)
  float plo0[ITEMS], plo1[ITEMS], plo2[ITEMS], phi0[ITEMS], phi1[ITEMS], phi2[ITEMS];
  float vb[ITEMS];
  unsigned invp[ITEMS];
  const int base = blockIdx.x * (256 * ITEMS);
#pragma unroll
  for (int k = 0; k < ITEMS; ++k) {
    const int p = base + k * 256 + tid;
    if (p < P) {
      const float* prf = priors + (size_t)p * 6;
      const float2 q0 = *(const float2*)(prf);
      const float2 q1 = *(const float2*)(prf + 2);
      const float2 q2 = *(const float2*)(prf + 4);
      plo0[k] = q0.x - q1.y * 0.5f; phi0[k] = q0.x + q1.y * 0.5f;
      plo1[k] = q0.y - q2.x * 0.5f; phi1[k] = q0.y + q2.x * 0.5f;
      plo2[k] = q1.x - q2.y * 0.5f; phi2[k] = q1.x + q2.y * 0.5f;
      vb[k] = ((phi0[k] - plo0[k]) * (phi1[k] - plo1[k])) * (phi2[k] - plo2[k]);
      invp[k] = 0xFFFFFFFFu - (unsigned)p;
    } else {  // far-away dummy prior: iou 0 against everything, invp 0 (never wins)
      plo0[k] = plo1[k] = plo2[k] = 1e18f;
      phi0[k] = phi1[k] = phi2[k] = 1e18f;
      vb[k] = 1e18f;
      invp[k] = 0u;
    }
  }

  const int bmax = min(BCH, B - b0);
  const int lane = tid & 63, wv = tid >> 6;
  for (int bb = 0; bb < bmax; ++bb) {
    float pkiou[NOBJ];
    unsigned pkinv[NOBJ];
#pragma unroll
    for (int o = 0; o < NOBJ; ++o) { pkiou[o] = 0.f; pkinv[o] = 0u; }
    float bestv[ITEMS];
    int bestobj[ITEMS];
#pragma unroll
    for (int k = 0; k < ITEMS; ++k) { bestv[k] = -1.f; bestobj[k] = 0; }

#pragma unroll
    for (int o = 0; o < NOBJ; ++o) {
      const float4 c0 = s_box[bb][o][0];
      const float4 c1 = s_box[bb][o][1];
#pragma unroll
      for (int k = 0; k < ITEMS; ++k) {
        const float d0 = fminf(c0.w, phi0[k]) - fmaxf(c0.x, plo0[k]);
        const float d1 = fminf(c1.x, phi1[k]) - fmaxf(c0.y, plo1[k]);
        const float d2 = fminf(c1.y, phi2[k]) - fmaxf(c0.z, plo2[k]);
        const float inter = (fmaxf(d0, 0.f) * fmaxf(d1, 0.f)) * fmaxf(d2, 0.f);
        const float un = (c1.z + vb[k]) - inter;
        const float iou = inter * __builtin_amdgcn_rcpf(un);
        if (iou > bestv[k]) { bestv[k] = iou; bestobj[k] = o; }  // first occurrence
        const bool gt = (iou > pkiou[o]) | ((iou == pkiou[o]) & (invp[k] > pkinv[o]));
        if (gt) { pkiou[o] = iou; pkinv[o] = invp[k]; }
      }
    }

    // wave butterfly reduce of packed (iou, invp), then cross-wave + global atomicMax
#pragma unroll
    for (int o = 0; o < NOBJ; ++o) {
      unsigned long long v =
          ((unsigned long long)__float_as_uint(pkiou[o]) << 32) | pkinv[o];
      for (int off = 1; off < 64; off <<= 1) {
        const unsigned long long w = __shfl_xor(v, off, 64);
        if (w > v) v = w;
      }
      if (lane == 0) s_part[wv][o] = v;
    }
    __syncthreads();
    if (tid < n_obj && tid < NOBJ) {
      unsigned long long v = s_part[0][tid];
      for (int w = 1; w < 4; ++w)
        if (s_part[w][tid] > v) v = s_part[w][tid];
      atomicMax(&prior_fo[(size_t)(b0 + bb) * n_obj + tid], v);
    }
#pragma unroll
    for (int k = 0; k < ITEMS; ++k) {
      const int p = base + k * 256 + tid;
      if (p < P) {
        best_u8[(size_t)(b0 + bb) * P + p] =
            (unsigned char)bestobj[k] | (bestv[k] >= 0.5f ? 0x80u : 0u);
      }
    }
    __syncthreads();  // protect s_part before next bb
  }
}

// Phase B: labels, CE, loc L1 for positives, conf_neg + fused radix round-0 hist.
template <int CC>
__global__ __launch_bounds__(256) void mbl_loss(
    const float* __restrict__ locs, const float* __restrict__ scores,
    const float* __restrict__ boxes, const int* __restrict__ labels,
    const float* __restrict__ priors, const unsigned long long* __restrict__ prior_fo,
    const unsigned char* __restrict__ best_u8, float* __restrict__ conf_neg,
    int* __restrict__ n_pos, double* __restrict__ sums, unsigned* __restrict__ hist,
    int P, int n_obj, int C) {
  const int b = blockIdx.y;
  const int p = blockIdx.x * 256 + threadIdx.x;
  const int tid = threadIdx.x;
  __shared__ float s_box[MAX_OBJ][6];
  __shared__ int s_lab[MAX_OBJ];
  __shared__ unsigned s_fo[MAX_OBJ];
  __shared__ unsigned s_hist[256];
  s_hist[tid] = 0u;
  for (int i = tid; i < n_obj * 6; i += 256)
    s_box[i / 6][i % 6] = boxes[(size_t)b * n_obj * 6 + i];
  for (int i = tid; i < n_obj; i += 256) {
    s_lab[i] = labels[(size_t)b * n_obj + i];
    s_fo[i] = 0xFFFFFFFFu - (unsigned)(prior_fo[(size_t)b * n_obj + i] & 0xFFFFFFFFull);
  }
  __syncthreads();

  int is_pos = 0;
  double confv = 0.0, locv = 0.0;
  if (p < P) {
    const unsigned char bp = best_u8[(size_t)b * P + p];
    int obj = bp & 0x7F;
    int posflag = bp >> 7;
    for (int o = 0; o < n_obj; ++o)  // forced matching, ascending = last wins
      if (s_fo[o] == (unsigned)p) { obj = o; posflag = 1; }
    const int lab = posflag ? s_lab[obj] : 0;

    float conf;
    if (CC == 2) {
      const float2 sc = *(const float2*)(scores + ((size_t)b * P + p) * 2);
      const float m = fmaxf(sc.x, sc.y);
      const float lse = m + __logf(__expf(sc.x - m) + __expf(sc.y - m));
      conf = (lab < 0) ? 0.f : (lse - ((lab == 0) ? sc.x : sc.y));
    } else {
      const float* sp = scores + ((size_t)b * P + p) * C;
      float m = sp[0];
      for (int c = 1; c < C; ++c) m = fmaxf(m, sp[c]);
      float se = 0.f;
      for (int c = 0; c < C; ++c) se += __expf(sp[c] - m);
      conf = (lab < 0) ? 0.f : (m + __logf(se) - sp[lab]);
    }

    float cn = conf;
    if (lab > 0) {
      is_pos = 1;
      confv = (double)conf;
      const float* pr = priors + (size_t)p * 6;
      const float* pl = locs + ((size_t)b * P + p) * 6;
      float ls = 0.f;
      for (int i = 0; i < 3; ++i) {
        const float c0 = (s_box[obj][i] + s_box[obj][i + 3]) * 0.5f;
        const float sz = s_box[obj][i + 3] - s_box[obj][i];
        const float g = (c0 - pr[i]) / (pr[i + 3] / 10.0f);
        const float g2 = logf(sz / pr[i + 3]) * 5.0f;
        ls += fabsf(pl[i] - g) + fabsf(pl[i + 3] - g2);
      }
      locv = (double)ls;
      cn = 0.f;
    }
    conf_neg[(size_t)b * P + p] = cn;
    atomicAdd(&s_hist[__float_as_uint(cn) >> 24], 1u);
  }

  // block reductions
  __shared__ int r_np[256];
  __shared__ double r_c[256];
  __shared__ double r_l[256];
  r_np[tid] = is_pos;
  r_c[tid] = confv;
  r_l[tid] = locv;
  __syncthreads();
  for (int s = 128; s > 0; s >>= 1) {
    if (tid < s) {
      r_np[tid] += r_np[tid + s];
      r_c[tid] += r_c[tid + s];
      r_l[tid] += r_l[tid + s];
    }
    __syncthreads();
  }
  if (tid == 0 && r_np[0] > 0) {
    atomicAdd(&n_pos[b], r_np[0]);
    atomicAdd(&sums[0], r_c[0]);
    atomicAdd(&sums[1], r_l[0]);
  }
  if (s_hist[tid]) atomicAdd(&hist[((size_t)b * 4 + 0) * 256 + tid], s_hist[tid]);
}

__device__ inline void select_chain(const unsigned* s_prev, int rounds, int K,
                                    unsigned* prefix_out, int* remk_out) {
  unsigned prefix = 0;
  int remk = K;
  for (int j = 0; j < rounds; ++j) {
    int acc = 0, sel = 0;
    for (int bin = 255; bin >= 0; --bin) {
      const int c = (int)s_prev[j * 256 + bin];
      if (acc + c >= remk) { sel = bin; break; }
      acc += c;
    }
    prefix |= (unsigned)sel << (24 - 8 * j);
    remk -= acc;
  }
  *prefix_out = prefix;
  *remk_out = remk;
}

// Radix rounds 1..3: recompute select chain from retained hists, then histogram.
__global__ __launch_bounds__(256) void mbl_hist_round(
    const float* __restrict__ conf_neg, const int* __restrict__ n_pos,
    unsigned* __restrict__ hist, int P, int round) {
  const int b = blockIdx.y;
  const int tid = threadIdx.x;
  __shared__ unsigned s_prev[3 * 256];
  __shared__ unsigned s_hist[256];
  __shared__ unsigned s_pr[2];
  s_hist[tid] = 0u;
  for (int j = 0; j < round; ++j)
    s_prev[j * 256 + tid] = hist[((size_t)b * 4 + j) * 256 + tid];
  __syncthreads();
  if (tid == 0) {
    int K = 3 * n_pos[b];
    if (K > P) K = P;
    unsigned prefix;
    int remk;
    select_chain(s_prev, round, K, &prefix, &remk);
    s_pr[0] = prefix;
    s_pr[1] = (unsigned)remk;
  }
  __syncthreads();
  const unsigned prefix = s_pr[0];
  const int shift = 24 - 8 * round;
  const unsigned maskHigh = 0xFFFFFFFFu << (shift + 8);
  const float* row = conf_neg + (size_t)b * P;
  const int n4 = P >> 2;
  const int per = (n4 + (int)gridDim.x - 1) / (int)gridDim.x;
  const int s4 = blockIdx.x * per, e4 = min(s4 + per, n4);
  for (int i = s4 + tid; i < e4; i += 256) {
    const float4 v = ((const float4*)row)[i];
    const unsigned u0 = __float_as_uint(v.x), u1 = __float_as_uint(v.y);
    const unsigned u2 = __float_as_uint(v.z), u3 = __float_as_uint(v.w);
    if ((u0 & maskHigh) == (prefix & maskHigh)) atomicAdd(&s_hist[(u0 >> shift) & 255u], 1u);
    if ((u1 & maskHigh) == (prefix & maskHigh)) atomicAdd(&s_hist[(u1 >> shift) & 255u], 1u);
    if ((u2 & maskHigh) == (prefix & maskHigh)) atomicAdd(&s_hist[(u2 >> shift) & 255u], 1u);
    if ((u3 & maskHigh) == (prefix & maskHigh)) atomicAdd(&s_hist[(u3 >> shift) & 255u], 1u);
  }
  if (blockIdx.x == 0) {  // scalar tail (P not multiple of 4)
    for (int p2 = (n4 << 2) + tid; p2 < P; p2 += 256) {
      const unsigned u = __float_as_uint(row[p2]);
      if ((u & maskHigh) == (prefix & maskHigh)) atomicAdd(&s_hist[(u >> shift) & 255u], 1u);
    }
  }
  __syncthreads();
  if (s_hist[tid]) atomicAdd(&hist[((size_t)b * 4 + round) * 256 + tid], s_hist[tid]);
}

// Final: sum of values strictly above threshold + remk ties; last block finalizes.
__global__ __launch_bounds__(256) void mbl_sum_final(
    const float* __restrict__ conf_neg, const int* __restrict__ n_pos,
    const unsigned* __restrict__ hist, double* __restrict__ sums,
    unsigned* __restrict__ counter, int P, int B, float* __restrict__ out) {
  const int b = blockIdx.y;
  const int tid = threadIdx.x;
  __shared__ unsigned s_prev[4 * 256];
  __shared__ unsigned s_pr[2];
  for (int j = 0; j < 4; ++j)
    s_prev[j * 256 + tid] = hist[((size_t)b * 4 + j) * 256 + tid];
  __syncthreads();
  if (tid == 0) {
    int K = 3 * n_pos[b];
    if (K > P) K = P;
    unsigned prefix;
    int remk;
    select_chain(s_prev, 4, K, &prefix, &remk);
    s_pr[0] = prefix;
    s_pr[1] = (unsigned)remk;
  }
  __syncthreads();
  const unsigned tbits = s_pr[0];
  const int remk = (int)s_pr[1];
  const float* row = conf_neg + (size_t)b * P;
  const int n4 = P >> 2;
  const int per = (n4 + (int)gridDim.x - 1) / (int)gridDim.x;
  const int s4 = blockIdx.x * per, e4 = min(s4 + per, n4);
  double local = 0.0;
  for (int i = s4 + tid; i < e4; i += 256) {
    const float4 v = ((const float4*)row)[i];
    if (__float_as_uint(v.x) > tbits) local += (double)v.x;
    if (__float_as_uint(v.y) > tbits) local += (double)v.y;
    if (__float_as_uint(v.z) > tbits) local += (double)v.z;
    if (__float_as_uint(v.w) > tbits) local += (double)v.w;
  }
  if (blockIdx.x == 0) {
    for (int p2 = (n4 << 2) + tid; p2 < P; p2 += 256) {
      const float v = row[p2];
      if (__float_as_uint(v) > tbits) local += (double)v;
    }
    if (tid == 0 && remk > 0)
      local += (double)remk * (double)__uint_as_float(tbits);
  }
  __shared__ double red[256];
  red[tid] = local;
  __syncthreads();
  for (int s = 128; s > 0; s >>= 1) {
    if (tid < s) red[tid] += red[tid + s];
    __syncthreads();
  }
  if (tid == 0) {
    if (red[0] != 0.0) atomicAdd(&sums[2], red[0]);
    __threadfence();
    const unsigned done = atomicAdd(counter, 1u);
    if (done == gridDim.x * gridDim.y - 1) {
      double tp = 0.0;
      for (int i = 0; i < B; ++i) tp += (double)n_pos[i];
      const double s0 = atomicAdd(&sums[0], 0.0);
      const double s1 = atomicAdd(&sums[1], 0.0);
      const double s2 = atomicAdd(&sums[2], 0.0);
      out[0] = (float)((s2 + s0) / tp);
      out[1] = (float)(s1 / (tp * 6.0));
    }
  }
}

extern "C" void kernel_launch(void* const* d_in, const int* in_sizes, int n_in,
                              void* d_out, int out_size, void* d_ws, size_t ws_size,
                              hipStream_t stream) {
  const float* locs = (const float*)d_in[0];
  const float* scores = (const float*)d_in[1];
  const float* boxes = (const float*)d_in[2];
  const int* labels = (const int*)d_in[3];
  const float* priors = (const float*)d_in[4];

  const long long sz_locs = (long long)in_sizes[0];
  const long long sz_scores = (long long)in_sizes[1];
  const long long sz_priors = (long long)in_sizes[4];
  const int P = (int)(sz_priors / 6);
  const int B = (int)(sz_locs / sz_priors);
  const int n_obj = in_sizes[3] / B;
  const int C = (int)(sz_scores * 6 / sz_locs);

  char* ws = (char*)d_ws;
  size_t off = 0;
  double* sums = (double*)(ws + off); off += 32;
  unsigned* counter = (unsigned*)(ws + off - 8);  // reuse pad slot
  int* n_pos = (int*)(ws + off); off += ((size_t)B * 4 + 15) & ~(size_t)15;
  unsigned long long* prior_fo = (unsigned long long*)(ws + off);
  off += (size_t)B * n_obj * 8;
  unsigned* hist = (unsigned*)(ws + off); off += (size_t)B * 4 * 256 * 4;
  float* conf_neg = (float*)(ws + off); off += ((size_t)B * P * 4 + 15) & ~(size_t)15;
  unsigned char* best_u8 = (unsigned char*)(ws + off); off += (size_t)B * P;
  (void)ws_size;

  const int histN = B * 4 * 256;
  int initN = histN;
  if (initN < B * n_obj) initN = B * n_obj;
  if (initN < 4) initN = 4;
  mbl_init<<<(initN + 255) / 256, 256, 0, stream>>>(sums, counter, n_pos, prior_fo, hist,
                                                    B, n_obj, histN);

  const dim3 mgrid((P + 256 * ITEMS - 1) / (256 * ITEMS), (B + BCH - 1) / BCH);
  if (n_obj <= 16) {
    mbl_match<16><<<mgrid, 256, 0, stream>>>(boxes, priors, prior_fo, best_u8, P, n_obj, B);
  } else if (n_obj <= 32) {
    mbl_match<32><<<mgrid, 256, 0, stream>>>(boxes, priors, prior_fo, best_u8, P, n_obj, B);
  } else {
    mbl_match<64><<<mgrid, 256, 0, stream>>>(boxes, priors, prior_fo, best_u8, P, n_obj, B);
  }

  const dim3 lgrid((P + 255) / 256, B);
  if (C == 2) {
    mbl_loss<2><<<lgrid, 256, 0, stream>>>(locs, scores, boxes, labels, priors, prior_fo,
                                           best_u8, conf_neg, n_pos, sums, hist, P, n_obj, C);
  } else {
    mbl_loss<0><<<lgrid, 256, 0, stream>>>(locs, scores, boxes, labels, priors, prior_fo,
                                           best_u8, conf_neg, n_pos, sums, hist, P, n_obj, C);
  }

  const dim3 tgrid(TOPK_CH, B);
  for (int round = 1; round <= 3; ++round)
    mbl_hist_round<<<tgrid, 256, 0, stream>>>(conf_neg, n_pos, hist, P, round);

  mbl_sum_final<<<tgrid, 256, 0, stream>>>(conf_neg, n_pos, hist, sums, counter, P, B,
                                           (float*)d_out);
}